// Round 1
// baseline (224.060 us; speedup 1.0000x reference)
//
#include <hip/hip_runtime.h>
#include <hip/hip_bf16.h>

#define BN 16
#define TN 2048
#define DN 64
#define EN 512

using f32x4  = __attribute__((ext_vector_type(4))) float;
using bf16x8 = __attribute__((ext_vector_type(8))) short;

static __device__ __forceinline__ short f2bf(float f) {
    __hip_bfloat16 h = __float2bfloat16(f);
    return __builtin_bit_cast(short, h);
}

// ---------------------------------------------------------------------------
// Kernel A: Q = x @ Wq + bq  (f32 accumulate), emit Q as bf16 row-major and
// bf16 transposed (QT[b][d][t]) for the PV pass.
// Block: 512 threads (8 waves). Each wave owns a 64-wide k-slice of W in
// registers; x rows broadcast from LDS; cross-wave k-reduction through LDS.
// Each block produces 64 consecutive rows (8 chunks of 8 rows).
// ---------------------------------------------------------------------------
__global__ __launch_bounds__(512, 4) void qproj_kernel(
    const float* __restrict__ x, const float* __restrict__ Wq,
    const float* __restrict__ bq, short* __restrict__ Qb,
    short* __restrict__ QTb)
{
    __shared__ float xlds[8][EN];      // 16 KB: 8 staged rows of x
    __shared__ float red[8][8][64];    // 16 KB: [row][wave(k-slice)][col]
    __shared__ short tl[64][68];       // 8.7 KB: [d][local row] bf16 (padded)

    const int tid = threadIdx.x;
    const int w = tid >> 6;            // wave id = k-slice
    const int c = tid & 63;            // output column d
    const int rowbase = blockIdx.x * 64;
    const int b = rowbase >> 11;
    const int tbase = rowbase & (TN - 1);

    // W slice into registers: W[w*64 + i][c]
    float wreg[64];
    #pragma unroll
    for (int i = 0; i < 64; ++i)
        wreg[i] = Wq[(w * 64 + i) * 64 + c];
    const float bias = bq[c];

    for (int ch = 0; ch < 8; ++ch) {
        // stage 8 rows of x (1024 float4, 2 per thread)
        const float4* xsrc =
            reinterpret_cast<const float4*>(x + (size_t)(rowbase + ch * 8) * EN);
        float4* xdst = reinterpret_cast<float4*>(&xlds[0][0]);
        xdst[tid] = xsrc[tid];
        xdst[tid + 512] = xsrc[tid + 512];
        __syncthreads();

        float acc[8];
        #pragma unroll
        for (int rr = 0; rr < 8; ++rr) {
            const float4* xp =
                reinterpret_cast<const float4*>(&xlds[rr][w * 64]);
            float a = 0.f;
            #pragma unroll
            for (int i = 0; i < 16; ++i) {
                float4 xv = xp[i];   // broadcast read (same addr across wave)
                a += xv.x * wreg[i * 4 + 0];
                a += xv.y * wreg[i * 4 + 1];
                a += xv.z * wreg[i * 4 + 2];
                a += xv.w * wreg[i * 4 + 3];
            }
            acc[rr] = a;
        }
        #pragma unroll
        for (int rr = 0; rr < 8; ++rr) red[rr][w][c] = acc[rr];
        __syncthreads();

        // reduce k-slices: this thread handles (row rr = w, col c)
        float q = bias;
        #pragma unroll
        for (int k = 0; k < 8; ++k) q += red[w][k][c];

        const int row = rowbase + ch * 8 + w;
        short qb = f2bf(q);
        Qb[(size_t)row * DN + c] = qb;
        tl[c][ch * 8 + w] = qb;
    }
    __syncthreads();

    // write QT[b][d][tbase..tbase+63] (1024 short4, 2 per thread)
    #pragma unroll
    for (int it = 0; it < 2; ++it) {
        int idx = it * 512 + tid;        // 0..1023
        int d = idx >> 4;
        int j4 = (idx & 15) * 4;
        short4 v = *reinterpret_cast<const short4*>(&tl[d][j4]);
        *reinterpret_cast<short4*>(
            &QTb[((size_t)(b * 64 + d)) * TN + tbase + j4]) = v;
    }
}

// ---------------------------------------------------------------------------
// Kernel B: column-softmax denominators. By symmetry of S, the column sum for
// column j equals the row sum of row j. Each wave owns 16 j-rows; loops over
// all i computing ST tiles via MFMA; accumulates sum(exp) per lane; shfl-xor
// reduce across the 16 column-lanes; stores 1/l.
// ---------------------------------------------------------------------------
__global__ __launch_bounds__(256, 4) void stats_kernel(
    const short* __restrict__ Qb, float* __restrict__ linv)
{
    const int tid = threadIdx.x;
    const int lane = tid & 63;
    const int wv = tid >> 6;
    const int c = lane & 15;
    const int g = lane >> 4;
    const int b = blockIdx.y;
    const int jbase = blockIdx.x * 64 + wv * 16;
    const short* Qbb = Qb + (size_t)b * TN * DN;

    // A frag: A[m][k] = Q[jbase+m][k], lane m = c, k = g*8 + t
    bf16x8 a0 = *reinterpret_cast<const bf16x8*>(Qbb + (size_t)(jbase + c) * DN + g * 8);
    bf16x8 a1 = *reinterpret_cast<const bf16x8*>(Qbb + (size_t)(jbase + c) * DN + g * 8 + 32);

    float l[4] = {0.f, 0.f, 0.f, 0.f};
    for (int ib = 0; ib < TN; ib += 16) {
        bf16x8 b0 = *reinterpret_cast<const bf16x8*>(Qbb + (size_t)(ib + c) * DN + g * 8);
        bf16x8 b1 = *reinterpret_cast<const bf16x8*>(Qbb + (size_t)(ib + c) * DN + g * 8 + 32);
        f32x4 acc = {0.f, 0.f, 0.f, 0.f};
        acc = __builtin_amdgcn_mfma_f32_16x16x32_bf16(a0, b0, acc, 0, 0, 0);
        acc = __builtin_amdgcn_mfma_f32_16x16x32_bf16(a1, b1, acc, 0, 0, 0);
        #pragma unroll
        for (int r = 0; r < 4; ++r)
            l[r] += __expf(acc[r] * 0.125f);
    }
    #pragma unroll
    for (int r = 0; r < 4; ++r) {
        float v = l[r];
        v += __shfl_xor(v, 1);
        v += __shfl_xor(v, 2);
        v += __shfl_xor(v, 4);
        v += __shfl_xor(v, 8);
        l[r] = v;
    }
    if (c == 0) {
        #pragma unroll
        for (int r = 0; r < 4; ++r)
            linv[(size_t)b * TN + jbase + g * 4 + r] = 1.0f / l[r];
    }
}

// ---------------------------------------------------------------------------
// Kernel C: out[i,:] = sum_j exp(s[i,j]) * (1/l_j) * Q[j,:]
// Swapped orientation: compute ST[j,i] tiles (A = Q[j-tiles], B = Q[i-block]^T)
// so the P->B-frag transpose needs only lane-uniform source registers.
// outT[d][i] accumulated via MFMA (A = QT rows d, B = P^T), transposed back
// through LDS in the epilogue.
// ---------------------------------------------------------------------------
__global__ __launch_bounds__(256, 4) void pv_kernel(
    const short* __restrict__ Qb, const short* __restrict__ QTb,
    const float* __restrict__ linv, float* __restrict__ out)
{
    __shared__ float olds[64][65];
    const int tid = threadIdx.x;
    const int lane = tid & 63;
    const int wv = tid >> 6;
    const int c = lane & 15;
    const int g = lane >> 4;
    const int b = blockIdx.y;
    const int iblock = blockIdx.x * 64;
    const int ibase = iblock + wv * 16;
    const short* Qbb = Qb + (size_t)b * TN * DN;
    const short* QTbb = QTb + (size_t)b * DN * TN;
    const float* linvb = linv + (size_t)b * TN;

    // invariant B frags: B[k=d][n=i] = Q[ibase+n][k]
    bf16x8 bi0 = *reinterpret_cast<const bf16x8*>(Qbb + (size_t)(ibase + c) * DN + g * 8);
    bf16x8 bi1 = *reinterpret_cast<const bf16x8*>(Qbb + (size_t)(ibase + c) * DN + g * 8 + 32);

    f32x4 o[4] = {{0.f,0.f,0.f,0.f},{0.f,0.f,0.f,0.f},{0.f,0.f,0.f,0.f},{0.f,0.f,0.f,0.f}};

    for (int jb = 0; jb < TN; jb += 32) {
        float p0[4], p1[4];
        {
            bf16x8 a0 = *reinterpret_cast<const bf16x8*>(Qbb + (size_t)(jb + c) * DN + g * 8);
            bf16x8 a1 = *reinterpret_cast<const bf16x8*>(Qbb + (size_t)(jb + c) * DN + g * 8 + 32);
            f32x4 acc = {0.f, 0.f, 0.f, 0.f};
            acc = __builtin_amdgcn_mfma_f32_16x16x32_bf16(a0, bi0, acc, 0, 0, 0);
            acc = __builtin_amdgcn_mfma_f32_16x16x32_bf16(a1, bi1, acc, 0, 0, 0);
            #pragma unroll
            for (int r = 0; r < 4; ++r)
                p0[r] = __expf(acc[r] * 0.125f) * linvb[jb + g * 4 + r];
        }
        {
            bf16x8 a0 = *reinterpret_cast<const bf16x8*>(Qbb + (size_t)(jb + 16 + c) * DN + g * 8);
            bf16x8 a1 = *reinterpret_cast<const bf16x8*>(Qbb + (size_t)(jb + 16 + c) * DN + g * 8 + 32);
            f32x4 acc = {0.f, 0.f, 0.f, 0.f};
            acc = __builtin_amdgcn_mfma_f32_16x16x32_bf16(a0, bi0, acc, 0, 0, 0);
            acc = __builtin_amdgcn_mfma_f32_16x16x32_bf16(a1, bi1, acc, 0, 0, 0);
            #pragma unroll
            for (int r = 0; r < 4; ++r)
                p1[r] = __expf(acc[r] * 0.125f) * linvb[jb + 16 + g * 4 + r];
        }

        // transpose P^T (D-layout) -> PV B-fragment
        // target lane (g,c), elem t: j_local = g*8+t; tile = g>>1;
        // jr = (g&1)*8 + t; srcLane = (jr>>2)*16 + c; srcReg = t&3.
        short bt[8];
        #pragma unroll
        for (int t = 0; t < 8; ++t) {
            int src = (2 * (g & 1) + (t >> 2)) * 16 + c;
            float va = __shfl(p0[t & 3], src);
            float vb = __shfl(p1[t & 3], src);
            bt[t] = f2bf((g < 2) ? va : vb);
        }
        bf16x8 bp;
        #pragma unroll
        for (int t = 0; t < 8; ++t) bp[t] = bt[t];

        // outT[d][i] += QT[d][j-slice] * P^T[j-slice][i]
        #pragma unroll
        for (int dt = 0; dt < 4; ++dt) {
            bf16x8 aq = *reinterpret_cast<const bf16x8*>(
                QTbb + (size_t)(dt * 16 + c) * TN + jb + g * 8);
            o[dt] = __builtin_amdgcn_mfma_f32_16x16x32_bf16(aq, bp, o[dt], 0, 0, 0);
        }
    }

    // epilogue: outT -> out via LDS transpose, coalesced stores
    #pragma unroll
    for (int dt = 0; dt < 4; ++dt) {
        #pragma unroll
        for (int r = 0; r < 4; ++r)
            olds[wv * 16 + c][dt * 16 + g * 4 + r] = o[dt][r];
    }
    __syncthreads();
    float* outb = out + (size_t)b * TN * DN + (size_t)iblock * DN;
    #pragma unroll
    for (int it = 0; it < 16; ++it) {
        int idx = it * 256 + tid;       // 0..4095
        int il = idx >> 6;
        int d = idx & 63;
        outb[idx] = olds[il][d];
    }
}

extern "C" void kernel_launch(void* const* d_in, const int* in_sizes, int n_in,
                              void* d_out, int out_size, void* d_ws, size_t ws_size,
                              hipStream_t stream) {
    const float* x  = (const float*)d_in[0];
    const float* Wq = (const float*)d_in[1];
    const float* bq = (const float*)d_in[2];
    float* out = (float*)d_out;

    short* Qb  = (short*)d_ws;                          // 4 MB
    short* QTb = Qb + (size_t)BN * TN * DN;             // 4 MB
    float* linv = (float*)(QTb + (size_t)BN * TN * DN); // 128 KB

    qproj_kernel<<<dim3(512), dim3(512), 0, stream>>>(x, Wq, bq, Qb, QTb);
    stats_kernel<<<dim3(TN / 64, BN), dim3(256), 0, stream>>>(Qb, linv);
    pv_kernel<<<dim3(TN / 64, BN), dim3(256), 0, stream>>>(Qb, QTb, linv, out);
}